// Round 1
// baseline (118.278 us; speedup 1.0000x reference)
//
#include <hip/hip_runtime.h>
#include <math.h>

#ifndef NSWEEP
#define NSWEEP 5   // cyclic Jacobi sweeps; 4x4 SPD well-conditioned -> quadratic conv.
#endif

#define EPSV 1e-8f

__device__ __forceinline__ float fast_sqrtf(float x) {
#if __has_builtin(__builtin_amdgcn_sqrtf)
  return __builtin_amdgcn_sqrtf(x);
#else
  return sqrtf(x);
#endif
}
__device__ __forceinline__ float fast_rcpf(float x) {
#if __has_builtin(__builtin_amdgcn_rcpf)
  return __builtin_amdgcn_rcpf(x);
#else
  return 1.0f / x;
#endif
}
__device__ __forceinline__ float fast_rsqf(float x) {
#if __has_builtin(__builtin_amdgcn_rsqf)
  return __builtin_amdgcn_rsqf(x);
#else
  return rsqrtf(x);
#endif
}
__device__ __forceinline__ float fast_logf(float x) {
#if __has_builtin(__builtin_amdgcn_logf)
  return __builtin_amdgcn_logf(x) * 0.6931471805599453f;  // v_log_f32 is log2
#else
  return logf(x);
#endif
}

// One Givens rotation (p,q) applied to symmetric A (10 unique entries, named
// scalars -> registers) and eigenvector accumulator V (16 named scalars).
// Branchless: apq==0 => t=0 => c=1,s=0 (identity). All indices compile-time.
#define JROT(APP, AQQ, APQ, AK1P, AK1Q, AK2P, AK2Q,                       \
             VP0, VQ0, VP1, VQ1, VP2, VQ2, VP3, VQ3)                      \
  do {                                                                    \
    float a_ = APQ;                                                       \
    float d_ = AQQ - APP;                                                 \
    float a2_ = a_ + a_;                                                  \
    float r_ = fast_sqrtf(fmaf(d_, d_, a2_ * a2_));                       \
    float den_ = fmaxf(fabsf(d_) + r_, 1e-30f);                          \
    /* num = 2a * sign(d): xor d's sign bit into 2a */                    \
    float num_ = __int_as_float(__float_as_int(a2_) ^                     \
                                (__float_as_int(d_) & 0x80000000));       \
    float t_ = num_ * fast_rcpf(den_);                                    \
    float c_ = fast_rsqf(fmaf(t_, t_, 1.0f));                             \
    float s_ = t_ * c_;                                                   \
    float ta_ = t_ * a_;                                                  \
    APP = APP - ta_;                                                      \
    AQQ = AQQ + ta_;                                                      \
    APQ = 0.0f;                                                           \
    {                                                                     \
      float kp_ = AK1P, kq_ = AK1Q;                                       \
      AK1P = fmaf(c_, kp_, -s_ * kq_);                                    \
      AK1Q = fmaf(s_, kp_, c_ * kq_);                                     \
    }                                                                     \
    {                                                                     \
      float kp_ = AK2P, kq_ = AK2Q;                                       \
      AK2P = fmaf(c_, kp_, -s_ * kq_);                                    \
      AK2Q = fmaf(s_, kp_, c_ * kq_);                                     \
    }                                                                     \
    {                                                                     \
      float p_ = VP0, q_ = VQ0;                                           \
      VP0 = fmaf(c_, p_, -s_ * q_);                                       \
      VQ0 = fmaf(s_, p_, c_ * q_);                                        \
    }                                                                     \
    {                                                                     \
      float p_ = VP1, q_ = VQ1;                                           \
      VP1 = fmaf(c_, p_, -s_ * q_);                                       \
      VQ1 = fmaf(s_, p_, c_ * q_);                                        \
    }                                                                     \
    {                                                                     \
      float p_ = VP2, q_ = VQ2;                                           \
      VP2 = fmaf(c_, p_, -s_ * q_);                                       \
      VQ2 = fmaf(s_, p_, c_ * q_);                                        \
    }                                                                     \
    {                                                                     \
      float p_ = VP3, q_ = VQ3;                                           \
      VP3 = fmaf(c_, p_, -s_ * q_);                                       \
      VQ3 = fmaf(s_, p_, c_ * q_);                                        \
    }                                                                     \
  } while (0)

__global__ __launch_bounds__(256) void TangentSpaceLayer_64141041598486_kernel(
    const float* __restrict__ x, float* __restrict__ out, int B) {
  __shared__ __align__(16) float so[256 * 10];
  const int t = threadIdx.x;
  const int m = blockIdx.x * 256 + t;

  if (m < B) {
    const float* p = x + (size_t)m * 16;
    float4 r0 = *(const float4*)(p + 0);
    float4 r1 = *(const float4*)(p + 4);
    float4 r2 = *(const float4*)(p + 8);
    float4 r3 = *(const float4*)(p + 12);

    // symmetrize + EPS*I  (upper-tri storage: a_ij with i<=j)
    float a00 = r0.x + EPSV;
    float a01 = 0.5f * (r0.y + r1.x);
    float a02 = 0.5f * (r0.z + r2.x);
    float a03 = 0.5f * (r0.w + r3.x);
    float a11 = r1.y + EPSV;
    float a12 = 0.5f * (r1.z + r2.y);
    float a13 = 0.5f * (r1.w + r3.y);
    float a22 = r2.z + EPSV;
    float a23 = 0.5f * (r2.w + r3.z);
    float a33 = r3.w + EPSV;

    float v00 = 1.f, v01 = 0.f, v02 = 0.f, v03 = 0.f;
    float v10 = 0.f, v11 = 1.f, v12 = 0.f, v13 = 0.f;
    float v20 = 0.f, v21 = 0.f, v22 = 1.f, v23 = 0.f;
    float v30 = 0.f, v31 = 0.f, v32 = 0.f, v33 = 1.f;

#pragma unroll 1
    for (int sweep = 0; sweep < NSWEEP; ++sweep) {
      // (p,q)=(0,1), k=2,3 : akp=(2,0)->a02,(2,1)->a12 ; (3,0)->a03,(3,1)->a13
      JROT(a00, a11, a01, a02, a12, a03, a13,
           v00, v01, v10, v11, v20, v21, v30, v31);
      // (0,2), k=1,3 : (1,0)->a01,(1,2)->a12 ; (3,0)->a03,(3,2)->a23
      JROT(a00, a22, a02, a01, a12, a03, a23,
           v00, v02, v10, v12, v20, v22, v30, v32);
      // (0,3), k=1,2 : (1,0)->a01,(1,3)->a13 ; (2,0)->a02,(2,3)->a23
      JROT(a00, a33, a03, a01, a13, a02, a23,
           v00, v03, v10, v13, v20, v23, v30, v33);
      // (1,2), k=0,3 : (0,1)->a01,(0,2)->a02 ; (3,1)->a13,(3,2)->a23
      JROT(a11, a22, a12, a01, a02, a13, a23,
           v01, v02, v11, v12, v21, v22, v31, v32);
      // (1,3), k=0,2 : (0,1)->a01,(0,3)->a03 ; (2,1)->a12,(2,3)->a23
      JROT(a11, a33, a13, a01, a03, a12, a23,
           v01, v03, v11, v13, v21, v23, v31, v33);
      // (2,3), k=0,1 : (0,2)->a02,(0,3)->a03 ; (1,2)->a12,(1,3)->a13
      JROT(a22, a33, a23, a02, a03, a12, a13,
           v02, v03, v12, v13, v22, v23, v32, v33);
    }

    // eigenvalues on the diagonal
    float lw0 = fast_logf(fmaxf(a00, EPSV));
    float lw1 = fast_logf(fmaxf(a11, EPSV));
    float lw2 = fast_logf(fmaxf(a22, EPSV));
    float lw3 = fast_logf(fmaxf(a33, EPSV));

    // W[i][k] = V[i][k] * lw[k];  out(i,j) = sum_k W[i][k] * V[j][k]
    float w00 = v00 * lw0, w01 = v01 * lw1, w02 = v02 * lw2, w03 = v03 * lw3;
    float w10 = v10 * lw0, w11 = v11 * lw1, w12 = v12 * lw2, w13 = v13 * lw3;
    float w20 = v20 * lw0, w21 = v21 * lw1, w22 = v22 * lw2, w23 = v23 * lw3;
    float w30 = v30 * lw0, w31 = v31 * lw1, w32 = v32 * lw2, w33 = v33 * lw3;

    float* sp = so + t * 10;
    sp[0] = fmaf(w00, v00, fmaf(w01, v01, fmaf(w02, v02, w03 * v03)));  // (0,0)
    sp[1] = fmaf(w00, v10, fmaf(w01, v11, fmaf(w02, v12, w03 * v13)));  // (0,1)
    sp[2] = fmaf(w00, v20, fmaf(w01, v21, fmaf(w02, v22, w03 * v23)));  // (0,2)
    sp[3] = fmaf(w00, v30, fmaf(w01, v31, fmaf(w02, v32, w03 * v33)));  // (0,3)
    sp[4] = fmaf(w10, v10, fmaf(w11, v11, fmaf(w12, v12, w13 * v13)));  // (1,1)
    sp[5] = fmaf(w10, v20, fmaf(w11, v21, fmaf(w12, v22, w13 * v23)));  // (1,2)
    sp[6] = fmaf(w10, v30, fmaf(w11, v31, fmaf(w12, v32, w13 * v33)));  // (1,3)
    sp[7] = fmaf(w20, v20, fmaf(w21, v21, fmaf(w22, v22, w23 * v23)));  // (2,2)
    sp[8] = fmaf(w20, v30, fmaf(w21, v31, fmaf(w22, v32, w23 * v33)));  // (2,3)
    sp[9] = fmaf(w30, v30, fmaf(w31, v31, fmaf(w32, v32, w33 * v33)));  // (3,3)
  }

  __syncthreads();

  // cooperative coalesced store of this block's [valid*10] floats
  const int valid = min(256, B - blockIdx.x * 256);
  const int nf = valid * 10;
  const int n4 = nf >> 2;
  float* obase = out + (size_t)blockIdx.x * 2560;
  const float4* s4 = (const float4*)so;
  float4* o4 = (float4*)obase;
  for (int i = t; i < n4; i += 256) o4[i] = s4[i];
  for (int i = n4 * 4 + t; i < nf; i += 256) obase[i] = so[i];
}

extern "C" void kernel_launch(void* const* d_in, const int* in_sizes, int n_in,
                              void* d_out, int out_size, void* d_ws, size_t ws_size,
                              hipStream_t stream) {
  const float* x = (const float*)d_in[0];
  float* out = (float*)d_out;
  const int B = in_sizes[0] / 16;
  const int blocks = (B + 255) / 256;
  hipLaunchKernelGGL(TangentSpaceLayer_64141041598486_kernel, dim3(blocks),
                     dim3(256), 0, stream, x, out, B);
}

// Round 4
// 113.399 us; speedup vs baseline: 1.0430x; 1.0430x over previous
//
#include <hip/hip_runtime.h>
#include <math.h>

#ifndef NSWEEP
#define NSWEEP 4   // cyclic Jacobi sweeps; 4x4 SPD converges quadratically:
                   // rel off-diag ~1e-8 after 4 sweeps, below fp32 eigh noise.
#endif

#define EPSV 1e-8f

__device__ __forceinline__ float fast_sqrtf(float x) {
#if __has_builtin(__builtin_amdgcn_sqrtf)
  return __builtin_amdgcn_sqrtf(x);
#else
  return sqrtf(x);
#endif
}
__device__ __forceinline__ float fast_rcpf(float x) {
#if __has_builtin(__builtin_amdgcn_rcpf)
  return __builtin_amdgcn_rcpf(x);
#else
  return 1.0f / x;
#endif
}
__device__ __forceinline__ float fast_rsqf(float x) {
#if __has_builtin(__builtin_amdgcn_rsqf)
  return __builtin_amdgcn_rsqf(x);
#else
  return rsqrtf(x);
#endif
}
__device__ __forceinline__ float fast_logf(float x) {
#if __has_builtin(__builtin_amdgcn_logf)
  return __builtin_amdgcn_logf(x) * 0.6931471805599453f;  // v_log_f32 is log2
#else
  return logf(x);
#endif
}

// One Givens rotation (p,q). Branchless: a==0 -> t=0 -> identity; d=a=0 ->
// den=1e-30, t=0 -> identity. Never NaN (FTZ flushes denormal a2 -> t=0).
#define JROT(APP, AQQ, APQ, AK1P, AK1Q, AK2P, AK2Q,                       \
             VP0, VQ0, VP1, VQ1, VP2, VQ2, VP3, VQ3)                      \
  do {                                                                    \
    float a_ = APQ;                                                       \
    float d_ = AQQ - APP;                                                 \
    float a2_ = a_ + a_;                                                  \
    float r_ = fast_sqrtf(fmaf(d_, d_, a2_ * a2_));                       \
    float den_ = fmaxf(fabsf(d_) + r_, 1e-30f);                          \
    float num_ = __int_as_float(__float_as_int(a2_) ^                     \
                                (__float_as_int(d_) & 0x80000000));       \
    float t_ = num_ * fast_rcpf(den_);                                    \
    float c_ = fast_rsqf(fmaf(t_, t_, 1.0f));                             \
    float s_ = t_ * c_;                                                   \
    float ta_ = t_ * a_;                                                  \
    APP = APP - ta_;                                                      \
    AQQ = AQQ + ta_;                                                      \
    APQ = 0.0f;                                                           \
    { float kp_ = AK1P, kq_ = AK1Q;                                       \
      AK1P = fmaf(c_, kp_, -s_ * kq_);                                    \
      AK1Q = fmaf(s_, kp_, c_ * kq_); }                                   \
    { float kp_ = AK2P, kq_ = AK2Q;                                       \
      AK2P = fmaf(c_, kp_, -s_ * kq_);                                    \
      AK2Q = fmaf(s_, kp_, c_ * kq_); }                                   \
    { float p_ = VP0, q_ = VQ0;                                           \
      VP0 = fmaf(c_, p_, -s_ * q_);                                       \
      VQ0 = fmaf(s_, p_, c_ * q_); }                                      \
    { float p_ = VP1, q_ = VQ1;                                           \
      VP1 = fmaf(c_, p_, -s_ * q_);                                       \
      VQ1 = fmaf(s_, p_, c_ * q_); }                                      \
    { float p_ = VP2, q_ = VQ2;                                           \
      VP2 = fmaf(c_, p_, -s_ * q_);                                       \
      VQ2 = fmaf(s_, p_, c_ * q_); }                                      \
    { float p_ = VP3, q_ = VQ3;                                           \
      VP3 = fmaf(c_, p_, -s_ * q_);                                       \
      VQ3 = fmaf(s_, p_, c_ * q_); }                                      \
  } while (0)

// Full pipeline for one matrix; all state in named scalars / compile-time
// indexed o[] -> registers. __forceinline__ into a single basic block so two
// adjacent calls interleave for ILP.
__device__ __forceinline__ void logm_one(float4 r0, float4 r1, float4 r2,
                                         float4 r3, float o[10]) {
  float a00 = r0.x + EPSV;
  float a01 = 0.5f * (r0.y + r1.x);
  float a02 = 0.5f * (r0.z + r2.x);
  float a03 = 0.5f * (r0.w + r3.x);
  float a11 = r1.y + EPSV;
  float a12 = 0.5f * (r1.z + r2.y);
  float a13 = 0.5f * (r1.w + r3.y);
  float a22 = r2.z + EPSV;
  float a23 = 0.5f * (r2.w + r3.z);
  float a33 = r3.w + EPSV;

  float v00 = 1.f, v01 = 0.f, v02 = 0.f, v03 = 0.f;
  float v10 = 0.f, v11 = 1.f, v12 = 0.f, v13 = 0.f;
  float v20 = 0.f, v21 = 0.f, v22 = 1.f, v23 = 0.f;
  float v30 = 0.f, v31 = 0.f, v32 = 0.f, v33 = 1.f;

#pragma unroll 1
  for (int sweep = 0; sweep < NSWEEP; ++sweep) {
    JROT(a00, a11, a01, a02, a12, a03, a13,
         v00, v01, v10, v11, v20, v21, v30, v31);
    JROT(a00, a22, a02, a01, a12, a03, a23,
         v00, v02, v10, v12, v20, v22, v30, v32);
    JROT(a00, a33, a03, a01, a13, a02, a23,
         v00, v03, v10, v13, v20, v23, v30, v33);
    JROT(a11, a22, a12, a01, a02, a13, a23,
         v01, v02, v11, v12, v21, v22, v31, v32);
    JROT(a11, a33, a13, a01, a03, a12, a23,
         v01, v03, v11, v13, v21, v23, v31, v33);
    JROT(a22, a33, a23, a02, a03, a12, a13,
         v02, v03, v12, v13, v22, v23, v32, v33);
  }

  float lw0 = fast_logf(fmaxf(a00, EPSV));
  float lw1 = fast_logf(fmaxf(a11, EPSV));
  float lw2 = fast_logf(fmaxf(a22, EPSV));
  float lw3 = fast_logf(fmaxf(a33, EPSV));

  float w00 = v00 * lw0, w01 = v01 * lw1, w02 = v02 * lw2, w03 = v03 * lw3;
  float w10 = v10 * lw0, w11 = v11 * lw1, w12 = v12 * lw2, w13 = v13 * lw3;
  float w20 = v20 * lw0, w21 = v21 * lw1, w22 = v22 * lw2, w23 = v23 * lw3;
  float w30 = v30 * lw0, w31 = v31 * lw1, w32 = v32 * lw2, w33 = v33 * lw3;

  o[0] = fmaf(w00, v00, fmaf(w01, v01, fmaf(w02, v02, w03 * v03)));
  o[1] = fmaf(w00, v10, fmaf(w01, v11, fmaf(w02, v12, w03 * v13)));
  o[2] = fmaf(w00, v20, fmaf(w01, v21, fmaf(w02, v22, w03 * v23)));
  o[3] = fmaf(w00, v30, fmaf(w01, v31, fmaf(w02, v32, w03 * v33)));
  o[4] = fmaf(w10, v10, fmaf(w11, v11, fmaf(w12, v12, w13 * v13)));
  o[5] = fmaf(w10, v20, fmaf(w11, v21, fmaf(w12, v22, w13 * v23)));
  o[6] = fmaf(w10, v30, fmaf(w11, v31, fmaf(w12, v32, w13 * v33)));
  o[7] = fmaf(w20, v20, fmaf(w21, v21, fmaf(w22, v22, w23 * v23)));
  o[8] = fmaf(w20, v30, fmaf(w21, v31, fmaf(w22, v32, w23 * v33)));
  o[9] = fmaf(w30, v30, fmaf(w31, v31, fmaf(w32, v32, w33 * v33)));
}

// 2 matrices per thread: two independent Jacobi chains in one basic block
// (clamped indices, no per-matrix branch) -> scheduler interleaves them and
// hides the serial sqrt->rcp->rsq dependency latency.
__global__ __launch_bounds__(256) void TangentSpaceLayer_64141041598486_kernel(
    const float* __restrict__ x, float* __restrict__ out, int B) {
  __shared__ __align__(16) float so[512 * 10];
  const int t = threadIdx.x;
  const int base = blockIdx.x * 512;
  // clamp instead of branch: tail block does redundant (discarded) work
  const int m0 = min(base + t, B - 1);
  const int m1 = min(base + 256 + t, B - 1);

  const float* p0 = x + (size_t)m0 * 16;
  const float* p1 = x + (size_t)m1 * 16;
  float4 a0 = *(const float4*)(p0 + 0);
  float4 a1 = *(const float4*)(p0 + 4);
  float4 a2 = *(const float4*)(p0 + 8);
  float4 a3 = *(const float4*)(p0 + 12);
  float4 b0 = *(const float4*)(p1 + 0);
  float4 b1 = *(const float4*)(p1 + 4);
  float4 b2 = *(const float4*)(p1 + 8);
  float4 b3 = *(const float4*)(p1 + 12);

  float oA[10], oB[10];
  logm_one(a0, a1, a2, a3, oA);
  logm_one(b0, b1, b2, b3, oB);

  float* spA = so + t * 10;
  float* spB = so + (t + 256) * 10;
#pragma unroll
  for (int i = 0; i < 10; ++i) spA[i] = oA[i];
#pragma unroll
  for (int i = 0; i < 10; ++i) spB[i] = oB[i];

  __syncthreads();

  // cooperative coalesced store of this block's [valid*10] floats
  const int valid = min(512, B - blockIdx.x * 512);
  const int nf = valid * 10;
  const int n4 = nf >> 2;
  float* obase = out + (size_t)blockIdx.x * 5120;
  const float4* s4 = (const float4*)so;
  float4* o4 = (float4*)obase;
  for (int i = t; i < n4; i += 256) o4[i] = s4[i];
  for (int i = n4 * 4 + t; i < nf; i += 256) obase[i] = so[i];
}

extern "C" void kernel_launch(void* const* d_in, const int* in_sizes, int n_in,
                              void* d_out, int out_size, void* d_ws, size_t ws_size,
                              hipStream_t stream) {
  const float* x = (const float*)d_in[0];
  float* out = (float*)d_out;
  const int B = in_sizes[0] / 16;
  const int blocks = (B + 511) / 512;
  hipLaunchKernelGGL(TangentSpaceLayer_64141041598486_kernel, dim3(blocks),
                     dim3(256), 0, stream, x, out, B);
}